// Round 11
// baseline (766.972 us; speedup 1.0000x reference)
//
#include <hip/hip_runtime.h>
#include <hip/hip_bf16.h>

#define N_NODES 50000
#define N_EDGES 800000
#define NUM_MOL 2000

typedef __attribute__((ext_vector_type(8))) short short8;
typedef __attribute__((ext_vector_type(4))) float f32x4;

union bfbits { __hip_bfloat16 b; short s; };

// ---------------------------------------------------------------------------
// Type tables.
// ---------------------------------------------------------------------------
__global__ void k_tables(const float* __restrict__ atom_table,
                         const float* __restrict__ bond_table,
                         const float* __restrict__ Wi,
                         const float* __restrict__ bi,
                         const float* __restrict__ Wu1,
                         const float* __restrict__ bu1,
                         float* __restrict__ T1, float* __restrict__ U1,
                         float* __restrict__ T2c, float* __restrict__ U2c) {
  int b = blockIdx.x;
  int c = threadIdx.x;
  if (b < 119) {
    float t = 0.f, u = 0.f;
    for (int k = 0; k < 128; k++) {
      float a = atom_table[b * 128 + k];
      t += a * Wi[k * 128 + c];
      u += a * Wu1[k * 128 + c];
    }
    T1[b * 128 + c] = t;
    U1[b * 128 + c] = u;
  } else {
    int a = b - 119;
    float t = bi[c], u = bu1[c];
    for (int k = 0; k < 64; k++) {
      float bv = bond_table[a * 64 + k];
      t += bv * Wi[(128 + k) * 128 + c];
      u += bv * Wu1[(128 + k) * 128 + c];
    }
    T2c[a * 128 + c] = t;
    U2c[a * 128 + c] = u;
  }
}

// Merged prep: b<476 -> TT rows; 476..603 -> Wt/Wlo; 604..731 -> W1t/W1lo.
__global__ void k_prep(const float* __restrict__ T1, const float* __restrict__ T2c,
                       const float* __restrict__ Wu2, const float* __restrict__ Wu1,
                       float* __restrict__ TT,
                       short* __restrict__ Wt, short* __restrict__ Wlo,
                       short* __restrict__ W1t, short* __restrict__ W1lo) {
  int b = blockIdx.x;
  int k = threadIdx.x;
  if (b < 476) {
    float v = T1[(b >> 2) * 128 + k] + T2c[(b & 3) * 128 + k];
    TT[b * 128 + k] = v > 0.f ? v : 0.f;
  } else if (b < 604) {
    int n = b - 476;
    float w = Wu2[k * 128 + n];
    bfbits hi; hi.b = __float2bfloat16(w);
    float hf = __bfloat162float(hi.b);
    bfbits lo; lo.b = __float2bfloat16(w - hf);
    Wt[n * 128 + k] = hi.s;
    Wlo[n * 128 + k] = lo.s;
  } else {
    int n = b - 604;
    float w = Wu1[(192 + k) * 128 + n];
    bfbits hi; hi.b = __float2bfloat16(w);
    float hf = __bfloat162float(hi.b);
    bfbits lo; lo.b = __float2bfloat16(w - hf);
    W1t[n * 128 + k] = hi.s;
    W1lo[n * 128 + k] = lo.s;
  }
}

// ---------------------------------------------------------------------------
// Padded-bucket CSR: csr[d*64 + pos], pos = atomicAdd(cnt[d],1).
// packed = (s*4+a) | ((x[s]*4+a) << 18)
// ~51 µs floor (round-1/2/3 dead ends: nt-drop neutral, two-pass binning
// worse). Keep as-is.
// ---------------------------------------------------------------------------
__global__ void k_fillb(const int* __restrict__ eidx, const int* __restrict__ attr,
                        const int* __restrict__ x,
                        int* __restrict__ cnt, int* __restrict__ csr1) {
  int e = blockIdx.x * 256 + threadIdx.x;
  int d = eidx[N_EDGES + e];
  int s = eidx[e];
  int a = attr[e];
  int pos = atomicAdd(&cnt[d], 1);
  if (pos < 64) {
    int packed = (s * 4 + a) | ((x[s] * 4 + a) << 18);
    csr1[d * 64 + pos] = packed;
  }
}

// molptr[m] = lower_bound(batch, m)
__global__ void k_molptr(const int* __restrict__ batch, int* __restrict__ molptr) {
  int m = blockIdx.x * 256 + threadIdx.x;
  if (m > NUM_MOL) return;
  int lo = 0, hi = N_NODES;
  while (lo < hi) {
    int mid = (lo + hi) >> 1;
    if (batch[mid] < m) lo = mid + 1; else hi = mid;
  }
  molptr[m] = lo;
}

// ---------------------------------------------------------------------------
// Gather initial messages: 8 edges per iter. idx = pk >> 18
// ---------------------------------------------------------------------------
__global__ void k_gather0(const int* __restrict__ cnt, const int* __restrict__ csr1,
                          const float* __restrict__ TT, float* __restrict__ A_) {
  int n = blockIdx.x * 4 + (threadIdx.x >> 6);
  int lane = threadIdx.x & 63;
  int g = lane >> 5;        // 0..1
  int p = lane & 31;        // channel quad
  int beg = n * 64;
  int end = beg + cnt[n];
  float s0 = 0.f, s1 = 0.f, s2 = 0.f, s3 = 0.f;
  int i = beg;
  for (; i + 7 < end; i += 8) {
    int iA = ((unsigned)csr1[i + g]) >> 18;
    int iB = ((unsigned)csr1[i + 2 + g]) >> 18;
    int iC = ((unsigned)csr1[i + 4 + g]) >> 18;
    int iD = ((unsigned)csr1[i + 6 + g]) >> 18;
    float4 va = *(const float4*)&TT[iA * 128 + p * 4];
    float4 vb = *(const float4*)&TT[iB * 128 + p * 4];
    float4 vc = *(const float4*)&TT[iC * 128 + p * 4];
    float4 vd = *(const float4*)&TT[iD * 128 + p * 4];
    s0 += (va.x + vb.x) + (vc.x + vd.x);
    s1 += (va.y + vb.y) + (vc.y + vd.y);
    s2 += (va.z + vb.z) + (vc.z + vd.z);
    s3 += (va.w + vb.w) + (vc.w + vd.w);
  }
  for (; i + 3 < end; i += 4) {
    int iA = ((unsigned)csr1[i + g]) >> 18;
    int iB = ((unsigned)csr1[i + 2 + g]) >> 18;
    float4 va = *(const float4*)&TT[iA * 128 + p * 4];
    float4 vb = *(const float4*)&TT[iB * 128 + p * 4];
    s0 += va.x + vb.x; s1 += va.y + vb.y;
    s2 += va.z + vb.z; s3 += va.w + vb.w;
  }
  for (; i < end; i += 2) {
    if (i + g < end) {
      int idx = ((unsigned)csr1[i + g]) >> 18;
      float4 v = *(const float4*)&TT[idx * 128 + p * 4];
      s0 += v.x; s1 += v.y; s2 += v.z; s3 += v.w;
    }
  }
  s0 += __shfl_xor(s0, 32, 64);
  s1 += __shfl_xor(s1, 32, 64);
  s2 += __shfl_xor(s2, 32, 64);
  s3 += __shfl_xor(s3, 32, 64);
  float2 o;
  o.x = (g == 0) ? s0 : s2;
  o.y = (g == 0) ? s1 : s3;
  *(float2*)&A_[n * 128 + p * 4 + g * 2] = o;
}

// ---------------------------------------------------------------------------
// Gather messages: 16 edges per iter. idx = pk & 0x3FFFF
// ---------------------------------------------------------------------------
__global__ void k_gather(const int* __restrict__ cnt, const int* __restrict__ csr1,
                         const __hip_bfloat16* __restrict__ M, float* __restrict__ A_) {
  int n = blockIdx.x * 4 + (threadIdx.x >> 6);
  int lane = threadIdx.x & 63;
  int g = lane >> 4;        // 0..3
  int p = lane & 15;        // channel octet
  int beg = n * 64;
  int end = beg + cnt[n];
  float s[8];
#pragma unroll
  for (int j = 0; j < 8; j++) s[j] = 0.f;
  const short* Ms = (const short*)M;
  int i = beg;
  for (; i + 15 < end; i += 16) {
    int iA = csr1[i + g] & 0x3FFFF;
    int iB = csr1[i + 4 + g] & 0x3FFFF;
    int iC = csr1[i + 8 + g] & 0x3FFFF;
    int iD = csr1[i + 12 + g] & 0x3FFFF;
    short8 va = *(const short8*)&Ms[iA * 128 + p * 8];
    short8 vb = *(const short8*)&Ms[iB * 128 + p * 8];
    short8 vc = *(const short8*)&Ms[iC * 128 + p * 8];
    short8 vd = *(const short8*)&Ms[iD * 128 + p * 8];
#pragma unroll
    for (int j = 0; j < 4; j++) {
      float2 fa = __bfloat1622float2(*(const __hip_bfloat162*)&((const short*)&va)[j * 2]);
      float2 fb = __bfloat1622float2(*(const __hip_bfloat162*)&((const short*)&vb)[j * 2]);
      float2 fc = __bfloat1622float2(*(const __hip_bfloat162*)&((const short*)&vc)[j * 2]);
      float2 fd = __bfloat1622float2(*(const __hip_bfloat162*)&((const short*)&vd)[j * 2]);
      s[j * 2] += (fa.x + fb.x) + (fc.x + fd.x);
      s[j * 2 + 1] += (fa.y + fb.y) + (fc.y + fd.y);
    }
  }
  for (; i + 7 < end; i += 8) {
    int iA = csr1[i + g] & 0x3FFFF;
    int iB = csr1[i + 4 + g] & 0x3FFFF;
    short8 va = *(const short8*)&Ms[iA * 128 + p * 8];
    short8 vb = *(const short8*)&Ms[iB * 128 + p * 8];
#pragma unroll
    for (int j = 0; j < 4; j++) {
      float2 fa = __bfloat1622float2(*(const __hip_bfloat162*)&((const short*)&va)[j * 2]);
      float2 fb = __bfloat1622float2(*(const __hip_bfloat162*)&((const short*)&vb)[j * 2]);
      s[j * 2] += fa.x + fb.x;
      s[j * 2 + 1] += fa.y + fb.y;
    }
  }
  for (; i < end; i += 4) {
    if (i + g < end) {
      int idx = csr1[i + g] & 0x3FFFF;
      short8 va = *(const short8*)&Ms[idx * 128 + p * 8];
#pragma unroll
      for (int j = 0; j < 4; j++) {
        float2 fa = __bfloat1622float2(*(const __hip_bfloat162*)&((const short*)&va)[j * 2]);
        s[j * 2] += fa.x;
        s[j * 2 + 1] += fa.y;
      }
    }
  }
#pragma unroll
  for (int j = 0; j < 8; j++) s[j] += __shfl_xor(s[j], 16, 64);
#pragma unroll
  for (int j = 0; j < 8; j++) s[j] += __shfl_xor(s[j], 32, 64);
  float2 o;
  o.x = s[g * 2];
  o.y = s[g * 2 + 1];
  *(float2*)&A_[n * 128 + p * 8 + g * 2] = o;
}

// ---------------------------------------------------------------------------
// k_mm1m v4 (round-9 win, keep): LDS-shared W1 half (h = blockIdx&1),
// XOR-swizzled; 3 blocks/CU. B2 = A@Wu1b + U1[x[n]].
// ---------------------------------------------------------------------------
__global__ __launch_bounds__(256, 2) void k_mm1m(const float* __restrict__ A_,
                                                 const short* __restrict__ W1t,
                                                 const short* __restrict__ W1lo,
                                                 const int* __restrict__ x,
                                                 const float* __restrict__ U1,
                                                 float* __restrict__ B2_) {
  __shared__ short wh[8192];           // 16 KB: W1-hi half, swizzled
  __shared__ short wl[8192];           // 16 KB: W1-lo half, swizzled
  __shared__ float mbuf[4][16][68];
  int t = threadIdx.x;
  int lane = t & 63;
  int m = lane & 15;
  int quad = lane >> 4;
  int wslot = t >> 6;
  int h = blockIdx.x & 1;

  for (int idx = t; idx < 1024; idx += 256) {
    int nl = idx >> 4;
    int c16 = idx & 15;
    int off = nl * 256 + c16 * 16;
    int so = (off ^ ((nl & 7) << 4)) >> 1;
    *(short8*)&wh[so] = *(const short8*)((const char*)W1t + (h * 64 + nl) * 256 + c16 * 16);
    *(short8*)&wl[so] = *(const short8*)((const char*)W1lo + (h * 64 + nl) * 256 + c16 * 16);
  }
  int nb[4], nx[4];
#pragma unroll
  for (int nt = 0; nt < 4; nt++) {
    int nl = nt * 16 + m;
    nb[nt] = nl * 256;
    nx[nt] = (nl & 7) << 4;
  }
  __syncthreads();

  for (int s = (blockIdx.x >> 1) * 4 + wslot; s < 3125; s += 2048) {
    int row = s * 16 + m;
    f32x4 acc[4];
#pragma unroll
    for (int nt = 0; nt < 4; nt++) acc[nt] = (f32x4){0.f, 0.f, 0.f, 0.f};

#pragma unroll
    for (int kc = 0; kc < 4; kc++) {
      int k0 = kc * 32 + quad * 8;
      short8 ahi, alo;
      {
        float av[8];
        *(float4*)&av[0] = *(const float4*)&A_[row * 128 + k0];
        *(float4*)&av[4] = *(const float4*)&A_[row * 128 + k0 + 4];
#pragma unroll
        for (int j = 0; j < 8; j++) {
          float hv = av[j];
          bfbits hi; hi.b = __float2bfloat16(hv);
          float hf = __bfloat162float(hi.b);
          bfbits lo; lo.b = __float2bfloat16(hv - hf);
          ahi[j] = hi.s;
          alo[j] = lo.s;
        }
      }
      int kb = k0 * 2;
#pragma unroll
      for (int nt = 0; nt < 4; nt++) {
        int so = ((nb[nt] + kb) ^ nx[nt]) >> 1;
        short8 whv = *(const short8*)&wh[so];
        short8 wlv = *(const short8*)&wl[so];
        acc[nt] = __builtin_amdgcn_mfma_f32_16x16x32_bf16(ahi, whv, acc[nt], 0, 0, 0);
        acc[nt] = __builtin_amdgcn_mfma_f32_16x16x32_bf16(alo, whv, acc[nt], 0, 0, 0);
        acc[nt] = __builtin_amdgcn_mfma_f32_16x16x32_bf16(ahi, wlv, acc[nt], 0, 0, 0);
      }
    }

#pragma unroll
    for (int nt = 0; nt < 4; nt++)
#pragma unroll
      for (int r = 0; r < 4; r++)
        mbuf[wslot][quad * 4 + r][nt * 16 + m] = acc[nt][r];
#pragma unroll
    for (int p = 0; p < 4; p++) {
      int c = p * 64 + lane;
      int rr = c >> 4;
      int qf = c & 15;
      int n = s * 16 + rr;
      int xn = x[n];
      float4 v = *(const float4*)&mbuf[wslot][rr][qf * 4];
      float4 d = *(const float4*)&U1[xn * 128 + h * 64 + qf * 4];
      v.x += d.x; v.y += d.y; v.z += d.z; v.w += d.w;
      *(float4*)&B2_[n * 128 + h * 64 + qf * 4] = v;
    }
  }
}

// ---------------------------------------------------------------------------
// k_mm2 v13: attr-reuse tile (v9 structure, verified correct) + LDS-shared
// weights (v12, round-8 win) + block-uniform h (round-9 trick, 32 KB not 64).
// Wave-task = (slab of 16 distinct nodes, half); inner attr loop reuses the
// 16 B2-row loads across 4 attrs -> 192 MFMAs per 16 loads (4x v12's ratio).
// Regs: acc[4][4]=64 + staging ~40 + addr ~25 ~= 130 << 256 (no spill; v9's
// spill came from in-reg weights, now in LDS). LDS = 32 KB W-half + 8.7 KB
// mbuf ~= 41 KB -> 3 blocks/CU = 12 waves/CU = 3 waves/SIMD (vs v12's 2).
// ---------------------------------------------------------------------------
__global__ __launch_bounds__(256, 2) void k_mm2(const float* __restrict__ B2_,
                                                const float* __restrict__ U2c,
                                                const short* __restrict__ Wt,
                                                const short* __restrict__ Wlo,
                                                const float* __restrict__ bu2,
                                                __hip_bfloat16* __restrict__ M) {
  __shared__ short wh[8192];           // 16 KB: W2-hi half, swizzled
  __shared__ short wl[8192];           // 16 KB: W2-lo half, swizzled
  __shared__ short mbuf[4][16][68];
  int t = threadIdx.x;
  int lane = t & 63;
  int m = lane & 15;        // node-local row 0..15
  int quad = lane >> 4;
  int wslot = t >> 6;
  int h = blockIdx.x & 1;

  // Stage this block's half of W2 (hi+lo), XOR swizzle off ^ ((nl&7)<<4).
  for (int idx = t; idx < 1024; idx += 256) {
    int nl = idx >> 4;
    int c16 = idx & 15;
    int off = nl * 256 + c16 * 16;
    int so = (off ^ ((nl & 7) << 4)) >> 1;
    *(short8*)&wh[so] = *(const short8*)((const char*)Wt + (h * 64 + nl) * 256 + c16 * 16);
    *(short8*)&wl[so] = *(const short8*)((const char*)Wlo + (h * 64 + nl) * 256 + c16 * 16);
  }
  float bias[4];
  int nb[4], nx[4];
#pragma unroll
  for (int nt = 0; nt < 4; nt++) {
    int nl = nt * 16 + m;
    bias[nt] = bu2[h * 64 + nl];
    nb[nt] = nl * 256;
    nx[nt] = (nl & 7) << 4;
  }
  __syncthreads();

  for (int s = (blockIdx.x >> 1) * 4 + wslot; s < 3125; s += 2048) {
    int row = s * 16 + m;      // 16 distinct nodes across m
    f32x4 acc[4][4];           // [attr][nt]
#pragma unroll
    for (int a = 0; a < 4; a++)
#pragma unroll
      for (int nt = 0; nt < 4; nt++) acc[a][nt] = (f32x4){0.f, 0.f, 0.f, 0.f};

#pragma unroll
    for (int kc = 0; kc < 4; kc++) {
      int k0 = kc * 32 + quad * 8;
      float bba[8];
      *(float4*)&bba[0] = *(const float4*)&B2_[row * 128 + k0];
      *(float4*)&bba[4] = *(const float4*)&B2_[row * 128 + k0 + 4];
      int kb = k0 * 2;
#pragma unroll
      for (int a = 0; a < 4; a++) {
        float u2a[8];
        *(float4*)&u2a[0] = *(const float4*)&U2c[a * 128 + k0];
        *(float4*)&u2a[4] = *(const float4*)&U2c[a * 128 + k0 + 4];
        short8 ahi, alo;
#pragma unroll
        for (int j = 0; j < 8; j++) {
          float hv = bba[j] + u2a[j];
          hv = hv > 0.f ? hv : 0.f;
          bfbits hi; hi.b = __float2bfloat16(hv);
          float hf = __bfloat162float(hi.b);
          bfbits lo; lo.b = __float2bfloat16(hv - hf);
          ahi[j] = hi.s;
          alo[j] = lo.s;
        }
#pragma unroll
        for (int nt = 0; nt < 4; nt++) {
          int so = ((nb[nt] + kb) ^ nx[nt]) >> 1;
          short8 whv = *(const short8*)&wh[so];
          short8 wlv = *(const short8*)&wl[so];
          acc[a][nt] = __builtin_amdgcn_mfma_f32_16x16x32_bf16(ahi, whv, acc[a][nt], 0, 0, 0);
          acc[a][nt] = __builtin_amdgcn_mfma_f32_16x16x32_bf16(alo, whv, acc[a][nt], 0, 0, 0);
          acc[a][nt] = __builtin_amdgcn_mfma_f32_16x16x32_bf16(ahi, wlv, acc[a][nt], 0, 0, 0);
        }
      }
    }

    // Epilogue per attr (v9's verified mapping): M row = (s*16 + rr)*4 + a.
#pragma unroll
    for (int a = 0; a < 4; a++) {
#pragma unroll
      for (int nt = 0; nt < 4; nt++) {
#pragma unroll
        for (int r = 0; r < 4; r++) {
          float v = acc[a][nt][r] + bias[nt];
          v = v > 0.f ? v : 0.f;
          bfbits o; o.b = __float2bfloat16(v);
          mbuf[wslot][quad * 4 + r][nt * 16 + m] = o.s;
        }
      }
      {
        int rr = lane >> 2;
        int qq = lane & 3;
        int mrow = (s * 16 + rr) * 4 + a;
        short8 v = *(const short8*)&mbuf[wslot][rr][qq * 8];
        *(short8*)((short*)M + mrow * 128 + h * 64 + qq * 8) = v;
        short8 v2 = *(const short8*)&mbuf[wslot][rr][(qq + 4) * 8];
        *(short8*)((short*)M + mrow * 128 + h * 64 + (qq + 4) * 8) = v2;
      }
    }
  }
}

// ---------------------------------------------------------------------------
// mol[m] = sum of A rows in [molptr[m], molptr[m+1]) — one wave per mol.
// ---------------------------------------------------------------------------
__global__ void k_molgather(const float* __restrict__ A_, const int* __restrict__ molptr,
                            float* __restrict__ mol) {
  int m = blockIdx.x * 4 + (threadIdx.x >> 6);
  int lane = threadIdx.x & 63;
  int beg = molptr[m], end = molptr[m + 1];
  float ax = 0.f, ay = 0.f;
  int n = beg;
  for (; n + 1 < end; n += 2) {
    float2 v0 = *(const float2*)&A_[n * 128 + lane * 2];
    float2 v1 = *(const float2*)&A_[(n + 1) * 128 + lane * 2];
    ax += v0.x + v1.x;
    ay += v0.y + v1.y;
  }
  if (n < end) {
    float2 v0 = *(const float2*)&A_[n * 128 + lane * 2];
    ax += v0.x;
    ay += v0.y;
  }
  float2 o; o.x = ax; o.y = ay;
  *(float2*)&mol[m * 128 + lane * 2] = o;
}

// ---------------------------------------------------------------------------
// out[m] = relu(mol[m] @ Wr1 + br1) @ Wr2 + br2  — 8 mols per block.
// ---------------------------------------------------------------------------
__global__ __launch_bounds__(256) void k_readout(const float* __restrict__ mol,
                                                 const float* __restrict__ Wr1,
                                                 const float* __restrict__ br1,
                                                 const float* __restrict__ Wr2,
                                                 const float* __restrict__ br2,
                                                 float* __restrict__ out) {
  int m0 = blockIdx.x * 8;
  __shared__ float ms[8][128];
  __shared__ float red[32];
  int t = threadIdx.x;
  int lane = t & 63;
  int wave = t >> 6;
  for (int i = t; i < 1024; i += 256)
    ms[i >> 7][i & 127] = mol[m0 * 128 + i];
  __syncthreads();
  float part[8];
#pragma unroll
  for (int q = 0; q < 8; q++) part[q] = 0.f;
#pragma unroll
  for (int jj = 0; jj < 2; jj++) {
    int j = t + jj * 256;
    float b1 = br1[j];
    float acc[8];
#pragma unroll
    for (int q = 0; q < 8; q++) acc[q] = b1;
    for (int k = 0; k < 128; k += 4) {
      float w0 = Wr1[k * 512 + j];
      float w1 = Wr1[(k + 1) * 512 + j];
      float w2 = Wr1[(k + 2) * 512 + j];
      float w3 = Wr1[(k + 3) * 512 + j];
#pragma unroll
      for (int q = 0; q < 8; q++)
        acc[q] += ms[q][k] * w0 + ms[q][k + 1] * w1 + ms[q][k + 2] * w2 + ms[q][k + 3] * w3;
    }
    float w2v = Wr2[j];
#pragma unroll
    for (int q = 0; q < 8; q++) {
      float a = acc[q] > 0.f ? acc[q] : 0.f;
      part[q] += a * w2v;
    }
  }
#pragma unroll
  for (int q = 0; q < 8; q++) {
    float v = part[q];
    v += __shfl_xor(v, 32, 64);
    v += __shfl_xor(v, 16, 64);
    v += __shfl_xor(v, 8, 64);
    v += __shfl_xor(v, 4, 64);
    v += __shfl_xor(v, 2, 64);
    v += __shfl_xor(v, 1, 64);
    if (lane == 0) red[wave * 8 + q] = v;
  }
  __syncthreads();
  if (t < 8)
    out[m0 + t] = red[t] + red[8 + t] + red[16 + t] + red[24 + t] + br2[0];
}

// ---------------------------------------------------------------------------
extern "C" void kernel_launch(void* const* d_in, const int* in_sizes, int n_in,
                              void* d_out, int out_size, void* d_ws, size_t ws_size,
                              hipStream_t stream) {
  const int* x        = (const int*)d_in[0];
  const int* eattr    = (const int*)d_in[1];
  const int* eidx     = (const int*)d_in[2];
  const int* batch    = (const int*)d_in[3];
  const float* atom_table = (const float*)d_in[4];
  const float* bond_table = (const float*)d_in[5];
  const float* Wi  = (const float*)d_in[6];
  const float* bi  = (const float*)d_in[7];
  const float* Wu1 = (const float*)d_in[8];
  const float* bu1 = (const float*)d_in[9];
  const float* Wu2 = (const float*)d_in[10];
  const float* bu2 = (const float*)d_in[11];
  const float* Wr1 = (const float*)d_in[12];
  const float* br1 = (const float*)d_in[13];
  const float* Wr2 = (const float*)d_in[14];
  const float* br2 = (const float*)d_in[15];
  float* out = (float*)d_out;

  char* ws = (char*)d_ws;
  __hip_bfloat16* M = (__hip_bfloat16*)(ws);       //  51,200,000 B (bf16)
  short* Wt      = (short*)(ws + 51200000);        //      32,768 B
  short* Wlo     = (short*)(ws + 51232768);        //      32,768 B
  short* W1t     = (short*)(ws + 51265536);        //      32,768 B
  short* W1lo    = (short*)(ws + 51298304);        //      32,768 B
  int*   molptr  = (int*)  (ws + 51331072);        //       8,004 B
  int*   cnt     = (int*)  (ws + 51340000);        //     200,000 B
  int*   csr1    = (int*)  (ws + 52000000);        //  12,800,000 B (64-slot buckets)
  float* A       = (float*)(ws + 102400000);       //  25,600,000 B
  float* B2      = (float*)(ws + 128000000);       //  25,600,000 B
  float* T1      = (float*)(ws + 157000064);       //      60,928 B
  float* U1      = (float*)(ws + 157060992);       //      60,928 B
  float* T2c     = (float*)(ws + 157121920);       //       2,048 B
  float* U2c     = (float*)(ws + 157123968);       //       2,048 B
  float* TT      = (float*)(ws + 157126016);       //     243,712 B
  float* mol     = (float*)(ws + 157369728);       //   1,024,000 B

  hipMemsetAsync(cnt, 0, N_NODES * sizeof(int), stream);
  k_tables<<<123, 128, 0, stream>>>(atom_table, bond_table, Wi, bi, Wu1, bu1,
                                    T1, U1, T2c, U2c);
  k_prep<<<732, 128, 0, stream>>>(T1, T2c, Wu2, Wu1, TT, Wt, Wlo, W1t, W1lo);
  k_fillb<<<N_EDGES / 256, 256, 0, stream>>>(eidx, eattr, x, cnt, csr1);
  k_molptr<<<(NUM_MOL + 256) / 256, 256, 0, stream>>>(batch, molptr);

  k_gather0<<<N_NODES / 4, 256, 0, stream>>>(cnt, csr1, TT, A);

  for (int p = 0; p < 4; p++) {
    k_mm1m<<<1024, 256, 0, stream>>>(A, W1t, W1lo, x, U1, B2);
    k_mm2<<<1024, 256, 0, stream>>>(B2, U2c, Wt, Wlo, bu2, M);
    k_gather<<<N_NODES / 4, 256, 0, stream>>>(cnt, csr1, M, A);
  }

  k_molgather<<<NUM_MOL / 4, 256, 0, stream>>>(A, molptr, mol);
  k_readout<<<NUM_MOL / 8, 256, 0, stream>>>(mol, Wr1, br1, Wr2, br2, out);
}

// Round 12
// 547.738 us; speedup vs baseline: 1.4003x; 1.4003x over previous
//
#include <hip/hip_runtime.h>
#include <hip/hip_bf16.h>

#define N_NODES 50000
#define N_EDGES 800000
#define NUM_MOL 2000

typedef __attribute__((ext_vector_type(8))) short short8;
typedef __attribute__((ext_vector_type(4))) float f32x4;

union bfbits { __hip_bfloat16 b; short s; };

// ---------------------------------------------------------------------------
// Type tables.
// ---------------------------------------------------------------------------
__global__ void k_tables(const float* __restrict__ atom_table,
                         const float* __restrict__ bond_table,
                         const float* __restrict__ Wi,
                         const float* __restrict__ bi,
                         const float* __restrict__ Wu1,
                         const float* __restrict__ bu1,
                         float* __restrict__ T1, float* __restrict__ U1,
                         float* __restrict__ T2c, float* __restrict__ U2c) {
  int b = blockIdx.x;
  int c = threadIdx.x;
  if (b < 119) {
    float t = 0.f, u = 0.f;
    for (int k = 0; k < 128; k++) {
      float a = atom_table[b * 128 + k];
      t += a * Wi[k * 128 + c];
      u += a * Wu1[k * 128 + c];
    }
    T1[b * 128 + c] = t;
    U1[b * 128 + c] = u;
  } else {
    int a = b - 119;
    float t = bi[c], u = bu1[c];
    for (int k = 0; k < 64; k++) {
      float bv = bond_table[a * 64 + k];
      t += bv * Wi[(128 + k) * 128 + c];
      u += bv * Wu1[(128 + k) * 128 + c];
    }
    T2c[a * 128 + c] = t;
    U2c[a * 128 + c] = u;
  }
}

// Merged prep: b<476 -> TT rows; 476..603 -> Wt/Wlo; 604..731 -> W1t/W1lo.
__global__ void k_prep(const float* __restrict__ T1, const float* __restrict__ T2c,
                       const float* __restrict__ Wu2, const float* __restrict__ Wu1,
                       float* __restrict__ TT,
                       short* __restrict__ Wt, short* __restrict__ Wlo,
                       short* __restrict__ W1t, short* __restrict__ W1lo) {
  int b = blockIdx.x;
  int k = threadIdx.x;
  if (b < 476) {
    float v = T1[(b >> 2) * 128 + k] + T2c[(b & 3) * 128 + k];
    TT[b * 128 + k] = v > 0.f ? v : 0.f;
  } else if (b < 604) {
    int n = b - 476;
    float w = Wu2[k * 128 + n];
    bfbits hi; hi.b = __float2bfloat16(w);
    float hf = __bfloat162float(hi.b);
    bfbits lo; lo.b = __float2bfloat16(w - hf);
    Wt[n * 128 + k] = hi.s;
    Wlo[n * 128 + k] = lo.s;
  } else {
    int n = b - 604;
    float w = Wu1[(192 + k) * 128 + n];
    bfbits hi; hi.b = __float2bfloat16(w);
    float hf = __bfloat162float(hi.b);
    bfbits lo; lo.b = __float2bfloat16(w - hf);
    W1t[n * 128 + k] = hi.s;
    W1lo[n * 128 + k] = lo.s;
  }
}

// ---------------------------------------------------------------------------
// Padded-bucket CSR: csr[d*64 + pos], pos = atomicAdd(cnt[d],1).
// packed = (s*4+a) | ((x[s]*4+a) << 18)
// ~51 µs floor (round-1/2/3 dead ends: nt-drop neutral, two-pass binning
// worse). Keep as-is.
// ---------------------------------------------------------------------------
__global__ void k_fillb(const int* __restrict__ eidx, const int* __restrict__ attr,
                        const int* __restrict__ x,
                        int* __restrict__ cnt, int* __restrict__ csr1) {
  int e = blockIdx.x * 256 + threadIdx.x;
  int d = eidx[N_EDGES + e];
  int s = eidx[e];
  int a = attr[e];
  int pos = atomicAdd(&cnt[d], 1);
  if (pos < 64) {
    int packed = (s * 4 + a) | ((x[s] * 4 + a) << 18);
    csr1[d * 64 + pos] = packed;
  }
}

// molptr[m] = lower_bound(batch, m)
__global__ void k_molptr(const int* __restrict__ batch, int* __restrict__ molptr) {
  int m = blockIdx.x * 256 + threadIdx.x;
  if (m > NUM_MOL) return;
  int lo = 0, hi = N_NODES;
  while (lo < hi) {
    int mid = (lo + hi) >> 1;
    if (batch[mid] < m) lo = mid + 1; else hi = mid;
  }
  molptr[m] = lo;
}

// ---------------------------------------------------------------------------
// Gather initial messages: 8 edges per iter. idx = pk >> 18
// ---------------------------------------------------------------------------
__global__ void k_gather0(const int* __restrict__ cnt, const int* __restrict__ csr1,
                          const float* __restrict__ TT, float* __restrict__ A_) {
  int n = blockIdx.x * 4 + (threadIdx.x >> 6);
  int lane = threadIdx.x & 63;
  int g = lane >> 5;        // 0..1
  int p = lane & 31;        // channel quad
  int beg = n * 64;
  int end = beg + cnt[n];
  float s0 = 0.f, s1 = 0.f, s2 = 0.f, s3 = 0.f;
  int i = beg;
  for (; i + 7 < end; i += 8) {
    int iA = ((unsigned)csr1[i + g]) >> 18;
    int iB = ((unsigned)csr1[i + 2 + g]) >> 18;
    int iC = ((unsigned)csr1[i + 4 + g]) >> 18;
    int iD = ((unsigned)csr1[i + 6 + g]) >> 18;
    float4 va = *(const float4*)&TT[iA * 128 + p * 4];
    float4 vb = *(const float4*)&TT[iB * 128 + p * 4];
    float4 vc = *(const float4*)&TT[iC * 128 + p * 4];
    float4 vd = *(const float4*)&TT[iD * 128 + p * 4];
    s0 += (va.x + vb.x) + (vc.x + vd.x);
    s1 += (va.y + vb.y) + (vc.y + vd.y);
    s2 += (va.z + vb.z) + (vc.z + vd.z);
    s3 += (va.w + vb.w) + (vc.w + vd.w);
  }
  for (; i + 3 < end; i += 4) {
    int iA = ((unsigned)csr1[i + g]) >> 18;
    int iB = ((unsigned)csr1[i + 2 + g]) >> 18;
    float4 va = *(const float4*)&TT[iA * 128 + p * 4];
    float4 vb = *(const float4*)&TT[iB * 128 + p * 4];
    s0 += va.x + vb.x; s1 += va.y + vb.y;
    s2 += va.z + vb.z; s3 += va.w + vb.w;
  }
  for (; i < end; i += 2) {
    if (i + g < end) {
      int idx = ((unsigned)csr1[i + g]) >> 18;
      float4 v = *(const float4*)&TT[idx * 128 + p * 4];
      s0 += v.x; s1 += v.y; s2 += v.z; s3 += v.w;
    }
  }
  s0 += __shfl_xor(s0, 32, 64);
  s1 += __shfl_xor(s1, 32, 64);
  s2 += __shfl_xor(s2, 32, 64);
  s3 += __shfl_xor(s3, 32, 64);
  float2 o;
  o.x = (g == 0) ? s0 : s2;
  o.y = (g == 0) ? s1 : s3;
  *(float2*)&A_[n * 128 + p * 4 + g * 2] = o;
}

// ---------------------------------------------------------------------------
// Gather messages: 16 edges per iter. idx = pk & 0x3FFFF
// ---------------------------------------------------------------------------
__global__ void k_gather(const int* __restrict__ cnt, const int* __restrict__ csr1,
                         const __hip_bfloat16* __restrict__ M, float* __restrict__ A_) {
  int n = blockIdx.x * 4 + (threadIdx.x >> 6);
  int lane = threadIdx.x & 63;
  int g = lane >> 4;        // 0..3
  int p = lane & 15;        // channel octet
  int beg = n * 64;
  int end = beg + cnt[n];
  float s[8];
#pragma unroll
  for (int j = 0; j < 8; j++) s[j] = 0.f;
  const short* Ms = (const short*)M;
  int i = beg;
  for (; i + 15 < end; i += 16) {
    int iA = csr1[i + g] & 0x3FFFF;
    int iB = csr1[i + 4 + g] & 0x3FFFF;
    int iC = csr1[i + 8 + g] & 0x3FFFF;
    int iD = csr1[i + 12 + g] & 0x3FFFF;
    short8 va = *(const short8*)&Ms[iA * 128 + p * 8];
    short8 vb = *(const short8*)&Ms[iB * 128 + p * 8];
    short8 vc = *(const short8*)&Ms[iC * 128 + p * 8];
    short8 vd = *(const short8*)&Ms[iD * 128 + p * 8];
#pragma unroll
    for (int j = 0; j < 4; j++) {
      float2 fa = __bfloat1622float2(*(const __hip_bfloat162*)&((const short*)&va)[j * 2]);
      float2 fb = __bfloat1622float2(*(const __hip_bfloat162*)&((const short*)&vb)[j * 2]);
      float2 fc = __bfloat1622float2(*(const __hip_bfloat162*)&((const short*)&vc)[j * 2]);
      float2 fd = __bfloat1622float2(*(const __hip_bfloat162*)&((const short*)&vd)[j * 2]);
      s[j * 2] += (fa.x + fb.x) + (fc.x + fd.x);
      s[j * 2 + 1] += (fa.y + fb.y) + (fc.y + fd.y);
    }
  }
  for (; i + 7 < end; i += 8) {
    int iA = csr1[i + g] & 0x3FFFF;
    int iB = csr1[i + 4 + g] & 0x3FFFF;
    short8 va = *(const short8*)&Ms[iA * 128 + p * 8];
    short8 vb = *(const short8*)&Ms[iB * 128 + p * 8];
#pragma unroll
    for (int j = 0; j < 4; j++) {
      float2 fa = __bfloat1622float2(*(const __hip_bfloat162*)&((const short*)&va)[j * 2]);
      float2 fb = __bfloat1622float2(*(const __hip_bfloat162*)&((const short*)&vb)[j * 2]);
      s[j * 2] += fa.x + fb.x;
      s[j * 2 + 1] += fa.y + fb.y;
    }
  }
  for (; i < end; i += 4) {
    if (i + g < end) {
      int idx = csr1[i + g] & 0x3FFFF;
      short8 va = *(const short8*)&Ms[idx * 128 + p * 8];
#pragma unroll
      for (int j = 0; j < 4; j++) {
        float2 fa = __bfloat1622float2(*(const __hip_bfloat162*)&((const short*)&va)[j * 2]);
        s[j * 2] += fa.x;
        s[j * 2 + 1] += fa.y;
      }
    }
  }
#pragma unroll
  for (int j = 0; j < 8; j++) s[j] += __shfl_xor(s[j], 16, 64);
#pragma unroll
  for (int j = 0; j < 8; j++) s[j] += __shfl_xor(s[j], 32, 64);
  float2 o;
  o.x = s[g * 2];
  o.y = s[g * 2 + 1];
  *(float2*)&A_[n * 128 + p * 8 + g * 2] = o;
}

// ---------------------------------------------------------------------------
// k_mm1m v4 (round-9 win, keep): LDS-shared W1 half (h = blockIdx&1),
// XOR-swizzled; 3 blocks/CU. B2 = A@Wu1b + U1[x[n]].
// ---------------------------------------------------------------------------
__global__ __launch_bounds__(256, 2) void k_mm1m(const float* __restrict__ A_,
                                                 const short* __restrict__ W1t,
                                                 const short* __restrict__ W1lo,
                                                 const int* __restrict__ x,
                                                 const float* __restrict__ U1,
                                                 float* __restrict__ B2_) {
  __shared__ short wh[8192];           // 16 KB: W1-hi half, swizzled
  __shared__ short wl[8192];           // 16 KB: W1-lo half, swizzled
  __shared__ float mbuf[4][16][68];
  int t = threadIdx.x;
  int lane = t & 63;
  int m = lane & 15;
  int quad = lane >> 4;
  int wslot = t >> 6;
  int h = blockIdx.x & 1;

  for (int idx = t; idx < 1024; idx += 256) {
    int nl = idx >> 4;
    int c16 = idx & 15;
    int off = nl * 256 + c16 * 16;
    int so = (off ^ ((nl & 7) << 4)) >> 1;
    *(short8*)&wh[so] = *(const short8*)((const char*)W1t + (h * 64 + nl) * 256 + c16 * 16);
    *(short8*)&wl[so] = *(const short8*)((const char*)W1lo + (h * 64 + nl) * 256 + c16 * 16);
  }
  int nb[4], nx[4];
#pragma unroll
  for (int nt = 0; nt < 4; nt++) {
    int nl = nt * 16 + m;
    nb[nt] = nl * 256;
    nx[nt] = (nl & 7) << 4;
  }
  __syncthreads();

  for (int s = (blockIdx.x >> 1) * 4 + wslot; s < 3125; s += 2048) {
    int row = s * 16 + m;
    f32x4 acc[4];
#pragma unroll
    for (int nt = 0; nt < 4; nt++) acc[nt] = (f32x4){0.f, 0.f, 0.f, 0.f};

#pragma unroll
    for (int kc = 0; kc < 4; kc++) {
      int k0 = kc * 32 + quad * 8;
      short8 ahi, alo;
      {
        float av[8];
        *(float4*)&av[0] = *(const float4*)&A_[row * 128 + k0];
        *(float4*)&av[4] = *(const float4*)&A_[row * 128 + k0 + 4];
#pragma unroll
        for (int j = 0; j < 8; j++) {
          float hv = av[j];
          bfbits hi; hi.b = __float2bfloat16(hv);
          float hf = __bfloat162float(hi.b);
          bfbits lo; lo.b = __float2bfloat16(hv - hf);
          ahi[j] = hi.s;
          alo[j] = lo.s;
        }
      }
      int kb = k0 * 2;
#pragma unroll
      for (int nt = 0; nt < 4; nt++) {
        int so = ((nb[nt] + kb) ^ nx[nt]) >> 1;
        short8 whv = *(const short8*)&wh[so];
        short8 wlv = *(const short8*)&wl[so];
        acc[nt] = __builtin_amdgcn_mfma_f32_16x16x32_bf16(ahi, whv, acc[nt], 0, 0, 0);
        acc[nt] = __builtin_amdgcn_mfma_f32_16x16x32_bf16(alo, whv, acc[nt], 0, 0, 0);
        acc[nt] = __builtin_amdgcn_mfma_f32_16x16x32_bf16(ahi, wlv, acc[nt], 0, 0, 0);
      }
    }

#pragma unroll
    for (int nt = 0; nt < 4; nt++)
#pragma unroll
      for (int r = 0; r < 4; r++)
        mbuf[wslot][quad * 4 + r][nt * 16 + m] = acc[nt][r];
#pragma unroll
    for (int p = 0; p < 4; p++) {
      int c = p * 64 + lane;
      int rr = c >> 4;
      int qf = c & 15;
      int n = s * 16 + rr;
      int xn = x[n];
      float4 v = *(const float4*)&mbuf[wslot][rr][qf * 4];
      float4 d = *(const float4*)&U1[xn * 128 + h * 64 + qf * 4];
      v.x += d.x; v.y += d.y; v.z += d.z; v.w += d.w;
      *(float4*)&B2_[n * 128 + h * 64 + qf * 4] = v;
    }
  }
}

// ---------------------------------------------------------------------------
// k_mm2 v14: v12's inner loop BYTE-FOR-BYTE (acc[4], proven no-spill, 547 µs
// config) + block-uniform h with half-size W staging (32 KB, v13's only
// individually-safe ingredient; functionally verified there). LDS = 32 KB
// + 8.7 KB mbuf ~= 41 KB -> 3 blocks/CU = 12 waves/CU (vs v12's 8).
// v9/v11/v13 attr-reuse tile is permanently abandoned: acc[4][4] + staging
// exceeds the 128-reg arch budget and spills (3 strikes).
// ---------------------------------------------------------------------------
__global__ __launch_bounds__(256, 2) void k_mm2(const float* __restrict__ B2_,
                                                const float* __restrict__ U2c,
                                                const short* __restrict__ Wt,
                                                const short* __restrict__ Wlo,
                                                const float* __restrict__ bu2,
                                                __hip_bfloat16* __restrict__ M) {
  __shared__ short wh[8192];           // 16 KB: W2-hi half, swizzled
  __shared__ short wl[8192];           // 16 KB: W2-lo half, swizzled
  __shared__ short mbuf[4][16][68];
  int t = threadIdx.x;
  int lane = t & 63;
  int m = lane & 15;
  int quad = lane >> 4;
  int wslot = t >> 6;
  int h = blockIdx.x & 1;

  // Stage this block's half of W2 (hi+lo), XOR swizzle off ^ ((nl&7)<<4).
  for (int idx = t; idx < 1024; idx += 256) {
    int nl = idx >> 4;
    int c16 = idx & 15;
    int off = nl * 256 + c16 * 16;
    int so = (off ^ ((nl & 7) << 4)) >> 1;
    *(short8*)&wh[so] = *(const short8*)((const char*)Wt + (h * 64 + nl) * 256 + c16 * 16);
    *(short8*)&wl[so] = *(const short8*)((const char*)Wlo + (h * 64 + nl) * 256 + c16 * 16);
  }
  float bias[4];
  int nb[4], nx[4];
#pragma unroll
  for (int nt = 0; nt < 4; nt++) {
    int nl = nt * 16 + m;
    bias[nt] = bu2[h * 64 + nl];
    nb[nt] = nl * 256;
    nx[nt] = (nl & 7) << 4;
  }
  __syncthreads();

  for (int s = (blockIdx.x >> 1) * 4 + wslot; s < 12500; s += 2048) {
    int node = s * 4 + (m >> 2);
    int attr = m & 3;
    f32x4 acc[4];
#pragma unroll
    for (int nt = 0; nt < 4; nt++) acc[nt] = (f32x4){0.f, 0.f, 0.f, 0.f};

#pragma unroll
    for (int kc = 0; kc < 4; kc++) {
      int k0 = kc * 32 + quad * 8;
      short8 ahi, alo;
      {
        float bba[8], u2a[8];
        *(float4*)&bba[0] = *(const float4*)&B2_[node * 128 + k0];
        *(float4*)&bba[4] = *(const float4*)&B2_[node * 128 + k0 + 4];
        *(float4*)&u2a[0] = *(const float4*)&U2c[attr * 128 + k0];
        *(float4*)&u2a[4] = *(const float4*)&U2c[attr * 128 + k0 + 4];
#pragma unroll
        for (int j = 0; j < 8; j++) {
          float hv = bba[j] + u2a[j];
          hv = hv > 0.f ? hv : 0.f;
          bfbits hi; hi.b = __float2bfloat16(hv);
          float hf = __bfloat162float(hi.b);
          bfbits lo; lo.b = __float2bfloat16(hv - hf);
          ahi[j] = hi.s;
          alo[j] = lo.s;
        }
      }
      int kb = k0 * 2;  // byte offset of k-range within a row
#pragma unroll
      for (int nt = 0; nt < 4; nt++) {
        int so = ((nb[nt] + kb) ^ nx[nt]) >> 1;
        short8 whv = *(const short8*)&wh[so];
        short8 wlv = *(const short8*)&wl[so];
        acc[nt] = __builtin_amdgcn_mfma_f32_16x16x32_bf16(ahi, whv, acc[nt], 0, 0, 0);
        acc[nt] = __builtin_amdgcn_mfma_f32_16x16x32_bf16(alo, whv, acc[nt], 0, 0, 0);
        acc[nt] = __builtin_amdgcn_mfma_f32_16x16x32_bf16(ahi, wlv, acc[nt], 0, 0, 0);
      }
    }

#pragma unroll
    for (int nt = 0; nt < 4; nt++) {
#pragma unroll
      for (int r = 0; r < 4; r++) {
        float v = acc[nt][r] + bias[nt];
        v = v > 0.f ? v : 0.f;
        bfbits o; o.b = __float2bfloat16(v);
        mbuf[wslot][quad * 4 + r][nt * 16 + m] = o.s;
      }
    }
    {
      int rr = lane >> 2;
      int qq = lane & 3;
      short8 v = *(const short8*)&mbuf[wslot][rr][qq * 8];
      *(short8*)((short*)M + (s * 16 + rr) * 128 + h * 64 + qq * 8) = v;
      short8 v2 = *(const short8*)&mbuf[wslot][rr][(qq + 4) * 8];
      *(short8*)((short*)M + (s * 16 + rr) * 128 + h * 64 + (qq + 4) * 8) = v2;
    }
  }
}

// ---------------------------------------------------------------------------
// mol[m] = sum of A rows in [molptr[m], molptr[m+1]) — one wave per mol.
// ---------------------------------------------------------------------------
__global__ void k_molgather(const float* __restrict__ A_, const int* __restrict__ molptr,
                            float* __restrict__ mol) {
  int m = blockIdx.x * 4 + (threadIdx.x >> 6);
  int lane = threadIdx.x & 63;
  int beg = molptr[m], end = molptr[m + 1];
  float ax = 0.f, ay = 0.f;
  int n = beg;
  for (; n + 1 < end; n += 2) {
    float2 v0 = *(const float2*)&A_[n * 128 + lane * 2];
    float2 v1 = *(const float2*)&A_[(n + 1) * 128 + lane * 2];
    ax += v0.x + v1.x;
    ay += v0.y + v1.y;
  }
  if (n < end) {
    float2 v0 = *(const float2*)&A_[n * 128 + lane * 2];
    ax += v0.x;
    ay += v0.y;
  }
  float2 o; o.x = ax; o.y = ay;
  *(float2*)&mol[m * 128 + lane * 2] = o;
}

// ---------------------------------------------------------------------------
// out[m] = relu(mol[m] @ Wr1 + br1) @ Wr2 + br2  — 8 mols per block.
// ---------------------------------------------------------------------------
__global__ __launch_bounds__(256) void k_readout(const float* __restrict__ mol,
                                                 const float* __restrict__ Wr1,
                                                 const float* __restrict__ br1,
                                                 const float* __restrict__ Wr2,
                                                 const float* __restrict__ br2,
                                                 float* __restrict__ out) {
  int m0 = blockIdx.x * 8;
  __shared__ float ms[8][128];
  __shared__ float red[32];
  int t = threadIdx.x;
  int lane = t & 63;
  int wave = t >> 6;
  for (int i = t; i < 1024; i += 256)
    ms[i >> 7][i & 127] = mol[m0 * 128 + i];
  __syncthreads();
  float part[8];
#pragma unroll
  for (int q = 0; q < 8; q++) part[q] = 0.f;
#pragma unroll
  for (int jj = 0; jj < 2; jj++) {
    int j = t + jj * 256;
    float b1 = br1[j];
    float acc[8];
#pragma unroll
    for (int q = 0; q < 8; q++) acc[q] = b1;
    for (int k = 0; k < 128; k += 4) {
      float w0 = Wr1[k * 512 + j];
      float w1 = Wr1[(k + 1) * 512 + j];
      float w2 = Wr1[(k + 2) * 512 + j];
      float w3 = Wr1[(k + 3) * 512 + j];
#pragma unroll
      for (int q = 0; q < 8; q++)
        acc[q] += ms[q][k] * w0 + ms[q][k + 1] * w1 + ms[q][k + 2] * w2 + ms[q][k + 3] * w3;
    }
    float w2v = Wr2[j];
#pragma unroll
    for (int q = 0; q < 8; q++) {
      float a = acc[q] > 0.f ? acc[q] : 0.f;
      part[q] += a * w2v;
    }
  }
#pragma unroll
  for (int q = 0; q < 8; q++) {
    float v = part[q];
    v += __shfl_xor(v, 32, 64);
    v += __shfl_xor(v, 16, 64);
    v += __shfl_xor(v, 8, 64);
    v += __shfl_xor(v, 4, 64);
    v += __shfl_xor(v, 2, 64);
    v += __shfl_xor(v, 1, 64);
    if (lane == 0) red[wave * 8 + q] = v;
  }
  __syncthreads();
  if (t < 8)
    out[m0 + t] = red[t] + red[8 + t] + red[16 + t] + red[24 + t] + br2[0];
}

// ---------------------------------------------------------------------------
extern "C" void kernel_launch(void* const* d_in, const int* in_sizes, int n_in,
                              void* d_out, int out_size, void* d_ws, size_t ws_size,
                              hipStream_t stream) {
  const int* x        = (const int*)d_in[0];
  const int* eattr    = (const int*)d_in[1];
  const int* eidx     = (const int*)d_in[2];
  const int* batch    = (const int*)d_in[3];
  const float* atom_table = (const float*)d_in[4];
  const float* bond_table = (const float*)d_in[5];
  const float* Wi  = (const float*)d_in[6];
  const float* bi  = (const float*)d_in[7];
  const float* Wu1 = (const float*)d_in[8];
  const float* bu1 = (const float*)d_in[9];
  const float* Wu2 = (const float*)d_in[10];
  const float* bu2 = (const float*)d_in[11];
  const float* Wr1 = (const float*)d_in[12];
  const float* br1 = (const float*)d_in[13];
  const float* Wr2 = (const float*)d_in[14];
  const float* br2 = (const float*)d_in[15];
  float* out = (float*)d_out;

  char* ws = (char*)d_ws;
  __hip_bfloat16* M = (__hip_bfloat16*)(ws);       //  51,200,000 B (bf16)
  short* Wt      = (short*)(ws + 51200000);        //      32,768 B
  short* Wlo     = (short*)(ws + 51232768);        //      32,768 B
  short* W1t     = (short*)(ws + 51265536);        //      32,768 B
  short* W1lo    = (short*)(ws + 51298304);        //      32,768 B
  int*   molptr  = (int*)  (ws + 51331072);        //       8,004 B
  int*   cnt     = (int*)  (ws + 51340000);        //     200,000 B
  int*   csr1    = (int*)  (ws + 52000000);        //  12,800,000 B (64-slot buckets)
  float* A       = (float*)(ws + 102400000);       //  25,600,000 B
  float* B2      = (float*)(ws + 128000000);       //  25,600,000 B
  float* T1      = (float*)(ws + 157000064);       //      60,928 B
  float* U1      = (float*)(ws + 157060992);       //      60,928 B
  float* T2c     = (float*)(ws + 157121920);       //       2,048 B
  float* U2c     = (float*)(ws + 157123968);       //       2,048 B
  float* TT      = (float*)(ws + 157126016);       //     243,712 B
  float* mol     = (float*)(ws + 157369728);       //   1,024,000 B

  hipMemsetAsync(cnt, 0, N_NODES * sizeof(int), stream);
  k_tables<<<123, 128, 0, stream>>>(atom_table, bond_table, Wi, bi, Wu1, bu1,
                                    T1, U1, T2c, U2c);
  k_prep<<<732, 128, 0, stream>>>(T1, T2c, Wu2, Wu1, TT, Wt, Wlo, W1t, W1lo);
  k_fillb<<<N_EDGES / 256, 256, 0, stream>>>(eidx, eattr, x, cnt, csr1);
  k_molptr<<<(NUM_MOL + 256) / 256, 256, 0, stream>>>(batch, molptr);

  k_gather0<<<N_NODES / 4, 256, 0, stream>>>(cnt, csr1, TT, A);

  for (int p = 0; p < 4; p++) {
    k_mm1m<<<1024, 256, 0, stream>>>(A, W1t, W1lo, x, U1, B2);
    k_mm2<<<1024, 256, 0, stream>>>(B2, U2c, Wt, Wlo, bu2, M);
    k_gather<<<N_NODES / 4, 256, 0, stream>>>(cnt, csr1, M, A);
  }

  k_molgather<<<NUM_MOL / 4, 256, 0, stream>>>(A, molptr, mol);
  k_readout<<<NUM_MOL / 8, 256, 0, stream>>>(mol, Wr1, br1, Wr2, br2, out);
}

// Round 13
// 535.569 us; speedup vs baseline: 1.4321x; 1.0227x over previous
//
#include <hip/hip_runtime.h>
#include <hip/hip_bf16.h>

#define N_NODES 50000
#define N_EDGES 800000
#define NUM_MOL 2000

typedef __attribute__((ext_vector_type(8))) short short8;
typedef __attribute__((ext_vector_type(4))) float f32x4;

union bfbits { __hip_bfloat16 b; short s; };

// ---------------------------------------------------------------------------
// k_pro1: merged prologue. Blocks 0..122 = type tables; 123..378 = weight
// hi/lo transposes; 379..386 = molptr; 387..3511 = fillb (CSR scatter).
// tables/transpose/molptr are independent of fillb, so their ~14 µs of work
// hides under fillb's 51 µs write-bound tail instead of running serially.
// ---------------------------------------------------------------------------
__global__ void k_pro1(const int* __restrict__ eidx, const int* __restrict__ eattr,
                       const int* __restrict__ x, const int* __restrict__ batch,
                       const float* __restrict__ atom_table,
                       const float* __restrict__ bond_table,
                       const float* __restrict__ Wi, const float* __restrict__ bi,
                       const float* __restrict__ Wu1, const float* __restrict__ bu1,
                       const float* __restrict__ Wu2,
                       float* __restrict__ T1, float* __restrict__ U1,
                       float* __restrict__ T2c, float* __restrict__ U2c,
                       short* __restrict__ Wt, short* __restrict__ Wlo,
                       short* __restrict__ W1t, short* __restrict__ W1lo,
                       int* __restrict__ molptr,
                       int* __restrict__ cnt, int* __restrict__ csr1) {
  int b = blockIdx.x;
  if (b < 123) {
    // --- type tables (128 active threads) ---
    if (threadIdx.x < 128) {
      int c = threadIdx.x;
      if (b < 119) {
        float t = 0.f, u = 0.f;
        for (int k = 0; k < 128; k++) {
          float a = atom_table[b * 128 + k];
          t += a * Wi[k * 128 + c];
          u += a * Wu1[k * 128 + c];
        }
        T1[b * 128 + c] = t;
        U1[b * 128 + c] = u;
      } else {
        int a = b - 119;
        float t = bi[c], u = bu1[c];
        for (int k = 0; k < 64; k++) {
          float bv = bond_table[a * 64 + k];
          t += bv * Wi[(128 + k) * 128 + c];
          u += bv * Wu1[(128 + k) * 128 + c];
        }
        T2c[a * 128 + c] = t;
        U2c[a * 128 + c] = u;
      }
    }
  } else if (b < 379) {
    // --- weight hi/lo transposes (128 active threads) ---
    if (threadIdx.x < 128) {
      int bb = b - 123;
      int k = threadIdx.x;
      if (bb < 128) {
        int n = bb;
        float w = Wu2[k * 128 + n];
        bfbits hi; hi.b = __float2bfloat16(w);
        float hf = __bfloat162float(hi.b);
        bfbits lo; lo.b = __float2bfloat16(w - hf);
        Wt[n * 128 + k] = hi.s;
        Wlo[n * 128 + k] = lo.s;
      } else {
        int n = bb - 128;
        float w = Wu1[(192 + k) * 128 + n];
        bfbits hi; hi.b = __float2bfloat16(w);
        float hf = __bfloat162float(hi.b);
        bfbits lo; lo.b = __float2bfloat16(w - hf);
        W1t[n * 128 + k] = hi.s;
        W1lo[n * 128 + k] = lo.s;
      }
    }
  } else if (b < 387) {
    // --- molptr: lower_bound(batch, m) ---
    int m = (b - 379) * 256 + threadIdx.x;
    if (m <= NUM_MOL) {
      int lo = 0, hi = N_NODES;
      while (lo < hi) {
        int mid = (lo + hi) >> 1;
        if (batch[mid] < m) lo = mid + 1; else hi = mid;
      }
      molptr[m] = lo;
    }
  } else {
    // --- fillb: padded-bucket CSR scatter (~51 µs floor, see round 1-3) ---
    int e = (b - 387) * 256 + threadIdx.x;
    int d = eidx[N_EDGES + e];
    int s = eidx[e];
    int a = eattr[e];
    int pos = atomicAdd(&cnt[d], 1);
    if (pos < 64) {
      int packed = (s * 4 + a) | ((x[s] * 4 + a) << 18);
      csr1[d * 64 + pos] = packed;
    }
  }
}

// TT rows depend on T1/T2c from k_pro1's table blocks — tiny follow-up kernel.
__global__ void k_prep_tt(const float* __restrict__ T1, const float* __restrict__ T2c,
                          float* __restrict__ TT) {
  int b = blockIdx.x;
  int k = threadIdx.x;
  float v = T1[(b >> 2) * 128 + k] + T2c[(b & 3) * 128 + k];
  TT[b * 128 + k] = v > 0.f ? v : 0.f;
}

// ---------------------------------------------------------------------------
// Gather initial messages: 8 edges per iter. idx = pk >> 18
// ---------------------------------------------------------------------------
__global__ void k_gather0(const int* __restrict__ cnt, const int* __restrict__ csr1,
                          const float* __restrict__ TT, float* __restrict__ A_) {
  int n = blockIdx.x * 4 + (threadIdx.x >> 6);
  int lane = threadIdx.x & 63;
  int g = lane >> 5;        // 0..1
  int p = lane & 31;        // channel quad
  int beg = n * 64;
  int end = beg + cnt[n];
  float s0 = 0.f, s1 = 0.f, s2 = 0.f, s3 = 0.f;
  int i = beg;
  for (; i + 7 < end; i += 8) {
    int iA = ((unsigned)csr1[i + g]) >> 18;
    int iB = ((unsigned)csr1[i + 2 + g]) >> 18;
    int iC = ((unsigned)csr1[i + 4 + g]) >> 18;
    int iD = ((unsigned)csr1[i + 6 + g]) >> 18;
    float4 va = *(const float4*)&TT[iA * 128 + p * 4];
    float4 vb = *(const float4*)&TT[iB * 128 + p * 4];
    float4 vc = *(const float4*)&TT[iC * 128 + p * 4];
    float4 vd = *(const float4*)&TT[iD * 128 + p * 4];
    s0 += (va.x + vb.x) + (vc.x + vd.x);
    s1 += (va.y + vb.y) + (vc.y + vd.y);
    s2 += (va.z + vb.z) + (vc.z + vd.z);
    s3 += (va.w + vb.w) + (vc.w + vd.w);
  }
  for (; i + 3 < end; i += 4) {
    int iA = ((unsigned)csr1[i + g]) >> 18;
    int iB = ((unsigned)csr1[i + 2 + g]) >> 18;
    float4 va = *(const float4*)&TT[iA * 128 + p * 4];
    float4 vb = *(const float4*)&TT[iB * 128 + p * 4];
    s0 += va.x + vb.x; s1 += va.y + vb.y;
    s2 += va.z + vb.z; s3 += va.w + vb.w;
  }
  for (; i < end; i += 2) {
    if (i + g < end) {
      int idx = ((unsigned)csr1[i + g]) >> 18;
      float4 v = *(const float4*)&TT[idx * 128 + p * 4];
      s0 += v.x; s1 += v.y; s2 += v.z; s3 += v.w;
    }
  }
  s0 += __shfl_xor(s0, 32, 64);
  s1 += __shfl_xor(s1, 32, 64);
  s2 += __shfl_xor(s2, 32, 64);
  s3 += __shfl_xor(s3, 32, 64);
  float2 o;
  o.x = (g == 0) ? s0 : s2;
  o.y = (g == 0) ? s1 : s3;
  *(float2*)&A_[n * 128 + p * 4 + g * 2] = o;
}

// ---------------------------------------------------------------------------
// Gather messages: 16 edges per iter. idx = pk & 0x3FFFF
// ---------------------------------------------------------------------------
__global__ void k_gather(const int* __restrict__ cnt, const int* __restrict__ csr1,
                         const __hip_bfloat16* __restrict__ M, float* __restrict__ A_) {
  int n = blockIdx.x * 4 + (threadIdx.x >> 6);
  int lane = threadIdx.x & 63;
  int g = lane >> 4;        // 0..3
  int p = lane & 15;        // channel octet
  int beg = n * 64;
  int end = beg + cnt[n];
  float s[8];
#pragma unroll
  for (int j = 0; j < 8; j++) s[j] = 0.f;
  const short* Ms = (const short*)M;
  int i = beg;
  for (; i + 15 < end; i += 16) {
    int iA = csr1[i + g] & 0x3FFFF;
    int iB = csr1[i + 4 + g] & 0x3FFFF;
    int iC = csr1[i + 8 + g] & 0x3FFFF;
    int iD = csr1[i + 12 + g] & 0x3FFFF;
    short8 va = *(const short8*)&Ms[iA * 128 + p * 8];
    short8 vb = *(const short8*)&Ms[iB * 128 + p * 8];
    short8 vc = *(const short8*)&Ms[iC * 128 + p * 8];
    short8 vd = *(const short8*)&Ms[iD * 128 + p * 8];
#pragma unroll
    for (int j = 0; j < 4; j++) {
      float2 fa = __bfloat1622float2(*(const __hip_bfloat162*)&((const short*)&va)[j * 2]);
      float2 fb = __bfloat1622float2(*(const __hip_bfloat162*)&((const short*)&vb)[j * 2]);
      float2 fc = __bfloat1622float2(*(const __hip_bfloat162*)&((const short*)&vc)[j * 2]);
      float2 fd = __bfloat1622float2(*(const __hip_bfloat162*)&((const short*)&vd)[j * 2]);
      s[j * 2] += (fa.x + fb.x) + (fc.x + fd.x);
      s[j * 2 + 1] += (fa.y + fb.y) + (fc.y + fd.y);
    }
  }
  for (; i + 7 < end; i += 8) {
    int iA = csr1[i + g] & 0x3FFFF;
    int iB = csr1[i + 4 + g] & 0x3FFFF;
    short8 va = *(const short8*)&Ms[iA * 128 + p * 8];
    short8 vb = *(const short8*)&Ms[iB * 128 + p * 8];
#pragma unroll
    for (int j = 0; j < 4; j++) {
      float2 fa = __bfloat1622float2(*(const __hip_bfloat162*)&((const short*)&va)[j * 2]);
      float2 fb = __bfloat1622float2(*(const __hip_bfloat162*)&((const short*)&vb)[j * 2]);
      s[j * 2] += fa.x + fb.x;
      s[j * 2 + 1] += fa.y + fb.y;
    }
  }
  for (; i < end; i += 4) {
    if (i + g < end) {
      int idx = csr1[i + g] & 0x3FFFF;
      short8 va = *(const short8*)&Ms[idx * 128 + p * 8];
#pragma unroll
      for (int j = 0; j < 4; j++) {
        float2 fa = __bfloat1622float2(*(const __hip_bfloat162*)&((const short*)&va)[j * 2]);
        s[j * 2] += fa.x;
        s[j * 2 + 1] += fa.y;
      }
    }
  }
#pragma unroll
  for (int j = 0; j < 8; j++) s[j] += __shfl_xor(s[j], 16, 64);
#pragma unroll
  for (int j = 0; j < 8; j++) s[j] += __shfl_xor(s[j], 32, 64);
  float2 o;
  o.x = s[g * 2];
  o.y = s[g * 2 + 1];
  *(float2*)&A_[n * 128 + p * 8 + g * 2] = o;
}

// ---------------------------------------------------------------------------
// k_mm1m v4 (round-9 win, keep): LDS-shared W1 half (h = blockIdx&1),
// XOR-swizzled; 3 blocks/CU. B2 = A@Wu1b + U1[x[n]].
// ---------------------------------------------------------------------------
__global__ __launch_bounds__(256, 2) void k_mm1m(const float* __restrict__ A_,
                                                 const short* __restrict__ W1t,
                                                 const short* __restrict__ W1lo,
                                                 const int* __restrict__ x,
                                                 const float* __restrict__ U1,
                                                 float* __restrict__ B2_) {
  __shared__ short wh[8192];           // 16 KB: W1-hi half, swizzled
  __shared__ short wl[8192];           // 16 KB: W1-lo half, swizzled
  __shared__ float mbuf[4][16][68];
  int t = threadIdx.x;
  int lane = t & 63;
  int m = lane & 15;
  int quad = lane >> 4;
  int wslot = t >> 6;
  int h = blockIdx.x & 1;

  for (int idx = t; idx < 1024; idx += 256) {
    int nl = idx >> 4;
    int c16 = idx & 15;
    int off = nl * 256 + c16 * 16;
    int so = (off ^ ((nl & 7) << 4)) >> 1;
    *(short8*)&wh[so] = *(const short8*)((const char*)W1t + (h * 64 + nl) * 256 + c16 * 16);
    *(short8*)&wl[so] = *(const short8*)((const char*)W1lo + (h * 64 + nl) * 256 + c16 * 16);
  }
  int nb[4], nx[4];
#pragma unroll
  for (int nt = 0; nt < 4; nt++) {
    int nl = nt * 16 + m;
    nb[nt] = nl * 256;
    nx[nt] = (nl & 7) << 4;
  }
  __syncthreads();

  for (int s = (blockIdx.x >> 1) * 4 + wslot; s < 3125; s += 2048) {
    int row = s * 16 + m;
    f32x4 acc[4];
#pragma unroll
    for (int nt = 0; nt < 4; nt++) acc[nt] = (f32x4){0.f, 0.f, 0.f, 0.f};

#pragma unroll
    for (int kc = 0; kc < 4; kc++) {
      int k0 = kc * 32 + quad * 8;
      short8 ahi, alo;
      {
        float av[8];
        *(float4*)&av[0] = *(const float4*)&A_[row * 128 + k0];
        *(float4*)&av[4] = *(const float4*)&A_[row * 128 + k0 + 4];
#pragma unroll
        for (int j = 0; j < 8; j++) {
          float hv = av[j];
          bfbits hi; hi.b = __float2bfloat16(hv);
          float hf = __bfloat162float(hi.b);
          bfbits lo; lo.b = __float2bfloat16(hv - hf);
          ahi[j] = hi.s;
          alo[j] = lo.s;
        }
      }
      int kb = k0 * 2;
#pragma unroll
      for (int nt = 0; nt < 4; nt++) {
        int so = ((nb[nt] + kb) ^ nx[nt]) >> 1;
        short8 whv = *(const short8*)&wh[so];
        short8 wlv = *(const short8*)&wl[so];
        acc[nt] = __builtin_amdgcn_mfma_f32_16x16x32_bf16(ahi, whv, acc[nt], 0, 0, 0);
        acc[nt] = __builtin_amdgcn_mfma_f32_16x16x32_bf16(alo, whv, acc[nt], 0, 0, 0);
        acc[nt] = __builtin_amdgcn_mfma_f32_16x16x32_bf16(ahi, wlv, acc[nt], 0, 0, 0);
      }
    }

#pragma unroll
    for (int nt = 0; nt < 4; nt++)
#pragma unroll
      for (int r = 0; r < 4; r++)
        mbuf[wslot][quad * 4 + r][nt * 16 + m] = acc[nt][r];
#pragma unroll
    for (int p = 0; p < 4; p++) {
      int c = p * 64 + lane;
      int rr = c >> 4;
      int qf = c & 15;
      int n = s * 16 + rr;
      int xn = x[n];
      float4 v = *(const float4*)&mbuf[wslot][rr][qf * 4];
      float4 d = *(const float4*)&U1[xn * 128 + h * 64 + qf * 4];
      v.x += d.x; v.y += d.y; v.z += d.z; v.w += d.w;
      *(float4*)&B2_[n * 128 + h * 64 + qf * 4] = v;
    }
  }
}

// ---------------------------------------------------------------------------
// k_mm2 v14 (547 µs config, keep): v12 inner loop (acc[4], no spill) +
// block-uniform h half-staging. Attr-reuse tile permanently abandoned
// (3 spills). mm2 is at its serial load->convert->MFMA chain floor.
// ---------------------------------------------------------------------------
__global__ __launch_bounds__(256, 2) void k_mm2(const float* __restrict__ B2_,
                                                const float* __restrict__ U2c,
                                                const short* __restrict__ Wt,
                                                const short* __restrict__ Wlo,
                                                const float* __restrict__ bu2,
                                                __hip_bfloat16* __restrict__ M) {
  __shared__ short wh[8192];           // 16 KB: W2-hi half, swizzled
  __shared__ short wl[8192];           // 16 KB: W2-lo half, swizzled
  __shared__ short mbuf[4][16][68];
  int t = threadIdx.x;
  int lane = t & 63;
  int m = lane & 15;
  int quad = lane >> 4;
  int wslot = t >> 6;
  int h = blockIdx.x & 1;

  for (int idx = t; idx < 1024; idx += 256) {
    int nl = idx >> 4;
    int c16 = idx & 15;
    int off = nl * 256 + c16 * 16;
    int so = (off ^ ((nl & 7) << 4)) >> 1;
    *(short8*)&wh[so] = *(const short8*)((const char*)Wt + (h * 64 + nl) * 256 + c16 * 16);
    *(short8*)&wl[so] = *(const short8*)((const char*)Wlo + (h * 64 + nl) * 256 + c16 * 16);
  }
  float bias[4];
  int nb[4], nx[4];
#pragma unroll
  for (int nt = 0; nt < 4; nt++) {
    int nl = nt * 16 + m;
    bias[nt] = bu2[h * 64 + nl];
    nb[nt] = nl * 256;
    nx[nt] = (nl & 7) << 4;
  }
  __syncthreads();

  for (int s = (blockIdx.x >> 1) * 4 + wslot; s < 12500; s += 2048) {
    int node = s * 4 + (m >> 2);
    int attr = m & 3;
    f32x4 acc[4];
#pragma unroll
    for (int nt = 0; nt < 4; nt++) acc[nt] = (f32x4){0.f, 0.f, 0.f, 0.f};

#pragma unroll
    for (int kc = 0; kc < 4; kc++) {
      int k0 = kc * 32 + quad * 8;
      short8 ahi, alo;
      {
        float bba[8], u2a[8];
        *(float4*)&bba[0] = *(const float4*)&B2_[node * 128 + k0];
        *(float4*)&bba[4] = *(const float4*)&B2_[node * 128 + k0 + 4];
        *(float4*)&u2a[0] = *(const float4*)&U2c[attr * 128 + k0];
        *(float4*)&u2a[4] = *(const float4*)&U2c[attr * 128 + k0 + 4];
#pragma unroll
        for (int j = 0; j < 8; j++) {
          float hv = bba[j] + u2a[j];
          hv = hv > 0.f ? hv : 0.f;
          bfbits hi; hi.b = __float2bfloat16(hv);
          float hf = __bfloat162float(hi.b);
          bfbits lo; lo.b = __float2bfloat16(hv - hf);
          ahi[j] = hi.s;
          alo[j] = lo.s;
        }
      }
      int kb = k0 * 2;  // byte offset of k-range within a row
#pragma unroll
      for (int nt = 0; nt < 4; nt++) {
        int so = ((nb[nt] + kb) ^ nx[nt]) >> 1;
        short8 whv = *(const short8*)&wh[so];
        short8 wlv = *(const short8*)&wl[so];
        acc[nt] = __builtin_amdgcn_mfma_f32_16x16x32_bf16(ahi, whv, acc[nt], 0, 0, 0);
        acc[nt] = __builtin_amdgcn_mfma_f32_16x16x32_bf16(alo, whv, acc[nt], 0, 0, 0);
        acc[nt] = __builtin_amdgcn_mfma_f32_16x16x32_bf16(ahi, wlv, acc[nt], 0, 0, 0);
      }
    }

#pragma unroll
    for (int nt = 0; nt < 4; nt++) {
#pragma unroll
      for (int r = 0; r < 4; r++) {
        float v = acc[nt][r] + bias[nt];
        v = v > 0.f ? v : 0.f;
        bfbits o; o.b = __float2bfloat16(v);
        mbuf[wslot][quad * 4 + r][nt * 16 + m] = o.s;
      }
    }
    {
      int rr = lane >> 2;
      int qq = lane & 3;
      short8 v = *(const short8*)&mbuf[wslot][rr][qq * 8];
      *(short8*)((short*)M + (s * 16 + rr) * 128 + h * 64 + qq * 8) = v;
      short8 v2 = *(const short8*)&mbuf[wslot][rr][(qq + 4) * 8];
      *(short8*)((short*)M + (s * 16 + rr) * 128 + h * 64 + (qq + 4) * 8) = v2;
    }
  }
}

// ---------------------------------------------------------------------------
// mol[m] = sum of A rows in [molptr[m], molptr[m+1]) — one wave per mol.
// ---------------------------------------------------------------------------
__global__ void k_molgather(const float* __restrict__ A_, const int* __restrict__ molptr,
                            float* __restrict__ mol) {
  int m = blockIdx.x * 4 + (threadIdx.x >> 6);
  int lane = threadIdx.x & 63;
  int beg = molptr[m], end = molptr[m + 1];
  float ax = 0.f, ay = 0.f;
  int n = beg;
  for (; n + 1 < end; n += 2) {
    float2 v0 = *(const float2*)&A_[n * 128 + lane * 2];
    float2 v1 = *(const float2*)&A_[(n + 1) * 128 + lane * 2];
    ax += v0.x + v1.x;
    ay += v0.y + v1.y;
  }
  if (n < end) {
    float2 v0 = *(const float2*)&A_[n * 128 + lane * 2];
    ax += v0.x;
    ay += v0.y;
  }
  float2 o; o.x = ax; o.y = ay;
  *(float2*)&mol[m * 128 + lane * 2] = o;
}

// ---------------------------------------------------------------------------
// out[m] = relu(mol[m] @ Wr1 + br1) @ Wr2 + br2  — 8 mols per block.
// ---------------------------------------------------------------------------
__global__ __launch_bounds__(256) void k_readout(const float* __restrict__ mol,
                                                 const float* __restrict__ Wr1,
                                                 const float* __restrict__ br1,
                                                 const float* __restrict__ Wr2,
                                                 const float* __restrict__ br2,
                                                 float* __restrict__ out) {
  int m0 = blockIdx.x * 8;
  __shared__ float ms[8][128];
  __shared__ float red[32];
  int t = threadIdx.x;
  int lane = t & 63;
  int wave = t >> 6;
  for (int i = t; i < 1024; i += 256)
    ms[i >> 7][i & 127] = mol[m0 * 128 + i];
  __syncthreads();
  float part[8];
#pragma unroll
  for (int q = 0; q < 8; q++) part[q] = 0.f;
#pragma unroll
  for (int jj = 0; jj < 2; jj++) {
    int j = t + jj * 256;
    float b1 = br1[j];
    float acc[8];
#pragma unroll
    for (int q = 0; q < 8; q++) acc[q] = b1;
    for (int k = 0; k < 128; k += 4) {
      float w0 = Wr1[k * 512 + j];
      float w1 = Wr1[(k + 1) * 512 + j];
      float w2 = Wr1[(k + 2) * 512 + j];
      float w3 = Wr1[(k + 3) * 512 + j];
#pragma unroll
      for (int q = 0; q < 8; q++)
        acc[q] += ms[q][k] * w0 + ms[q][k + 1] * w1 + ms[q][k + 2] * w2 + ms[q][k + 3] * w3;
    }
    float w2v = Wr2[j];
#pragma unroll
    for (int q = 0; q < 8; q++) {
      float a = acc[q] > 0.f ? acc[q] : 0.f;
      part[q] += a * w2v;
    }
  }
#pragma unroll
  for (int q = 0; q < 8; q++) {
    float v = part[q];
    v += __shfl_xor(v, 32, 64);
    v += __shfl_xor(v, 16, 64);
    v += __shfl_xor(v, 8, 64);
    v += __shfl_xor(v, 4, 64);
    v += __shfl_xor(v, 2, 64);
    v += __shfl_xor(v, 1, 64);
    if (lane == 0) red[wave * 8 + q] = v;
  }
  __syncthreads();
  if (t < 8)
    out[m0 + t] = red[t] + red[8 + t] + red[16 + t] + red[24 + t] + br2[0];
}

// ---------------------------------------------------------------------------
extern "C" void kernel_launch(void* const* d_in, const int* in_sizes, int n_in,
                              void* d_out, int out_size, void* d_ws, size_t ws_size,
                              hipStream_t stream) {
  const int* x        = (const int*)d_in[0];
  const int* eattr    = (const int*)d_in[1];
  const int* eidx     = (const int*)d_in[2];
  const int* batch    = (const int*)d_in[3];
  const float* atom_table = (const float*)d_in[4];
  const float* bond_table = (const float*)d_in[5];
  const float* Wi  = (const float*)d_in[6];
  const float* bi  = (const float*)d_in[7];
  const float* Wu1 = (const float*)d_in[8];
  const float* bu1 = (const float*)d_in[9];
  const float* Wu2 = (const float*)d_in[10];
  const float* bu2 = (const float*)d_in[11];
  const float* Wr1 = (const float*)d_in[12];
  const float* br1 = (const float*)d_in[13];
  const float* Wr2 = (const float*)d_in[14];
  const float* br2 = (const float*)d_in[15];
  float* out = (float*)d_out;

  char* ws = (char*)d_ws;
  __hip_bfloat16* M = (__hip_bfloat16*)(ws);       //  51,200,000 B (bf16)
  short* Wt      = (short*)(ws + 51200000);        //      32,768 B
  short* Wlo     = (short*)(ws + 51232768);        //      32,768 B
  short* W1t     = (short*)(ws + 51265536);        //      32,768 B
  short* W1lo    = (short*)(ws + 51298304);        //      32,768 B
  int*   molptr  = (int*)  (ws + 51331072);        //       8,004 B
  int*   cnt     = (int*)  (ws + 51340000);        //     200,000 B
  int*   csr1    = (int*)  (ws + 52000000);        //  12,800,000 B (64-slot buckets)
  float* A       = (float*)(ws + 102400000);       //  25,600,000 B
  float* B2      = (float*)(ws + 128000000);       //  25,600,000 B
  float* T1      = (float*)(ws + 157000064);       //      60,928 B
  float* U1      = (float*)(ws + 157060992);       //      60,928 B
  float* T2c     = (float*)(ws + 157121920);       //       2,048 B
  float* U2c     = (float*)(ws + 157123968);       //       2,048 B
  float* TT      = (float*)(ws + 157126016);       //     243,712 B
  float* mol     = (float*)(ws + 157369728);       //   1,024,000 B

  hipMemsetAsync(cnt, 0, N_NODES * sizeof(int), stream);
  // Merged prologue: tables + weight transposes + molptr hide under fillb.
  k_pro1<<<3512, 256, 0, stream>>>(eidx, eattr, x, batch,
                                   atom_table, bond_table, Wi, bi, Wu1, bu1, Wu2,
                                   T1, U1, T2c, U2c, Wt, Wlo, W1t, W1lo,
                                   molptr, cnt, csr1);
  k_prep_tt<<<476, 128, 0, stream>>>(T1, T2c, TT);

  k_gather0<<<N_NODES / 4, 256, 0, stream>>>(cnt, csr1, TT, A);

  for (int p = 0; p < 4; p++) {
    k_mm1m<<<1024, 256, 0, stream>>>(A, W1t, W1lo, x, U1, B2);
    k_mm2<<<1024, 256, 0, stream>>>(B2, U2c, Wt, Wlo, bu2, M);
    k_gather<<<N_NODES / 4, 256, 0, stream>>>(cnt, csr1, M, A);
  }

  k_molgather<<<NUM_MOL / 4, 256, 0, stream>>>(A, molptr, mol);
  k_readout<<<NUM_MOL / 8, 256, 0, stream>>>(mol, Wr1, br1, Wr2, br2, out);
}